// Round 1
// baseline (15631.503 us; speedup 1.0000x reference)
//
#include <hip/hip_runtime.h>

#define Tn 512
#define Bn 64
#define In 128
#define Hn 1024
#define GBn 16    // batch rows per group
#define NGn 4     // independent batch groups
#define NBLKn 64  // blocks per group
#define NCOLn 16  // H columns per block

typedef __attribute__((ext_vector_type(8))) short short8;
typedef __attribute__((ext_vector_type(4))) float f32x4;

__device__ __forceinline__ short f2bf(float f) {
  unsigned u = __builtin_bit_cast(unsigned, f);
  unsigned r = u + 0x7FFFu + ((u >> 16) & 1u);  // RTNE
  return (short)(r >> 16);
}
__device__ __forceinline__ float bf2f(unsigned short s) {
  return __builtin_bit_cast(float, ((unsigned)s) << 16);
}
__device__ __forceinline__ float sigm(float x) { return 1.f / (1.f + __expf(-x)); }
__device__ __forceinline__ float tanh_f(float x) {
  float ax = fabsf(x);
  float e = __expf(-2.f * ax);
  float t = (1.f - e) / (1.f + e);
  return x < 0.f ? -t : t;
}

// Monotonic-phase group barrier. Release: __threadfence (L2 writeback) before
// arrival; acquire: spin with agent-scope acquire loads + __threadfence after.
__device__ __forceinline__ void gbar(unsigned* cnt, unsigned* flag,
                                     unsigned nblk, unsigned target) {
  __syncthreads();
  if (threadIdx.x == 0) {
    __threadfence();
    unsigned prev = __hip_atomic_fetch_add(cnt, 1u, __ATOMIC_ACQ_REL,
                                           __HIP_MEMORY_SCOPE_AGENT);
    if (prev == nblk - 1u) {
      __hip_atomic_store(cnt, 0u, __ATOMIC_RELAXED, __HIP_MEMORY_SCOPE_AGENT);
      __hip_atomic_store(flag, target, __ATOMIC_RELEASE, __HIP_MEMORY_SCOPE_AGENT);
    } else {
      while (__hip_atomic_load(flag, __ATOMIC_ACQUIRE,
                               __HIP_MEMORY_SCOPE_AGENT) < target) { }
    }
    __threadfence();
  }
  __syncthreads();
}

// x (f32) -> bf16 bits, one shot.
__global__ void __launch_bounds__(256) xcvt_kernel(const float* __restrict__ x,
                                                   unsigned short* __restrict__ xb) {
  size_t idx = ((size_t)blockIdx.x * 256 + threadIdx.x) * 8;
  float4 a0 = *(const float4*)(x + idx);
  float4 a1 = *(const float4*)(x + idx + 4);
  short8 w;
  w[0] = f2bf(a0.x); w[1] = f2bf(a0.y); w[2] = f2bf(a0.z); w[3] = f2bf(a0.w);
  w[4] = f2bf(a1.x); w[5] = f2bf(a1.y); w[6] = f2bf(a1.z); w[7] = f2bf(a1.w);
  *(short8*)(xb + idx) = w;
}

__global__ void __launch_bounds__(256, 1) lstm_kernel(
    const unsigned short* __restrict__ xb, const float* __restrict__ W_ih,
    const float* __restrict__ W_hh, const float* __restrict__ b_ih,
    const float* __restrict__ b_hh, float* __restrict__ hs_f32,
    unsigned short* __restrict__ hs_b16, unsigned short* __restrict__ pp,
    unsigned* __restrict__ bar, int f32mode) {
  const int bid = blockIdx.x;
  const int grp = bid >> 6;   // batch group 0..3
  const int hc = bid & 63;    // H-chunk 0..63 (16 cols each)
  const int wid = threadIdx.x >> 6;  // wave = gate (i,f,g,o)
  const int lane = threadIdx.x & 63;
  const int rowsel = lane & 15;
  const int k8 = (lane >> 4) * 8;

  __shared__ float gates_s[4][16][16];
  __shared__ float bias_s[4][16];

  if (threadIdx.x < 64) {
    int gg = threadIdx.x >> 4, cc = threadIdx.x & 15;
    int idx = gg * Hn + hc * NCOLn + cc;
    bias_s[gg][cc] = b_ih[idx] + b_hh[idx];
  }

  // --- weights -> registers (B-fragments, bf16 bits). One-time. ---
  const int wrow = wid * Hn + hc * NCOLn + rowsel;  // gate row in [0,4096)
  short8 whh[32];
#pragma unroll
  for (int kt = 0; kt < 32; ++kt) {
    const float* p = W_hh + (size_t)wrow * Hn + kt * 32 + k8;
    float4 a0 = *(const float4*)p;
    float4 a1 = *(const float4*)(p + 4);
    short8 w;
    w[0] = f2bf(a0.x); w[1] = f2bf(a0.y); w[2] = f2bf(a0.z); w[3] = f2bf(a0.w);
    w[4] = f2bf(a1.x); w[5] = f2bf(a1.y); w[6] = f2bf(a1.z); w[7] = f2bf(a1.w);
    whh[kt] = w;
  }
  short8 wih[4];
#pragma unroll
  for (int kt = 0; kt < 4; ++kt) {
    const float* p = W_ih + (size_t)wrow * In + kt * 32 + k8;
    float4 a0 = *(const float4*)p;
    float4 a1 = *(const float4*)(p + 4);
    short8 w;
    w[0] = f2bf(a0.x); w[1] = f2bf(a0.y); w[2] = f2bf(a0.z); w[3] = f2bf(a0.w);
    w[4] = f2bf(a1.x); w[5] = f2bf(a1.y); w[6] = f2bf(a1.z); w[7] = f2bf(a1.w);
    wih[kt] = w;
  }
  __syncthreads();

  unsigned short* ppg = pp + (size_t)grp * 2 * GBn * Hn;
  unsigned* cnt = bar + grp * 64;
  unsigned* flag = bar + grp * 64 + 32;

  const unsigned short* xrow = xb + (size_t)(grp * GBn + rowsel) * (Tn * In);

  const int prow = threadIdx.x >> 4;  // batch row 0..15 (pointwise owner)
  const int pcol = threadIdx.x & 15;  // H col within chunk
  float c_reg = 0.f;

#pragma clang loop unroll(disable)
  for (int t = 0; t < Tn; ++t) {
    f32x4 acc[4];
#pragma unroll
    for (int q = 0; q < 4; ++q) acc[q] = (f32x4){0.f, 0.f, 0.f, 0.f};

    short8 a[36];
    const unsigned short* hp =
        ppg + ((t & 1) ^ 1) * (GBn * Hn) + rowsel * Hn + k8;
    if (t > 0) {
#pragma unroll
      for (int kt = 0; kt < 32; ++kt) a[kt] = *(const short8*)(hp + kt * 32);
    }
    {
      const unsigned short* xp = xrow + (size_t)t * In + k8;
#pragma unroll
      for (int kt = 0; kt < 4; ++kt) a[32 + kt] = *(const short8*)(xp + kt * 32);
    }

    if (t > 0) {
#pragma unroll
      for (int kt = 0; kt < 36; ++kt)
        acc[kt & 3] = __builtin_amdgcn_mfma_f32_16x16x32_bf16(
            a[kt], kt < 32 ? whh[kt] : wih[kt - 32], acc[kt & 3], 0, 0, 0);
    } else {
#pragma unroll
      for (int kt = 0; kt < 4; ++kt)
        acc[kt] = __builtin_amdgcn_mfma_f32_16x16x32_bf16(a[32 + kt], wih[kt],
                                                          acc[kt], 0, 0, 0);
    }
    f32x4 asum = (acc[0] + acc[1]) + (acc[2] + acc[3]);
#pragma unroll
    for (int r = 0; r < 4; ++r)
      gates_s[wid][(lane >> 4) * 4 + r][lane & 15] = asum[r];
    __syncthreads();

    // pointwise LSTM cell; thread owns (prow, pcol), c stays in register
    float iv = gates_s[0][prow][pcol] + bias_s[0][pcol];
    float fv = gates_s[1][prow][pcol] + bias_s[1][pcol];
    float gv = gates_s[2][prow][pcol] + bias_s[2][pcol];
    float ov = gates_s[3][prow][pcol] + bias_s[3][pcol];
    float ig = sigm(iv), fg = sigm(fv), og = sigm(ov), gt = tanh_f(gv);
    c_reg = fg * c_reg + ig * gt;
    float hval = og * tanh_f(c_reg);
    unsigned short hb = (unsigned short)f2bf(hval);
    ppg[(t & 1) * (GBn * Hn) + prow * Hn + hc * NCOLn + pcol] = hb;
    size_t hsidx = ((size_t)t * Bn + grp * GBn + prow) * Hn + hc * NCOLn + pcol;
    if (f32mode) hs_f32[hsidx] = hval;
    else         hs_b16[hsidx] = hb;

    gbar(cnt, flag, NBLKn, (unsigned)(t + 1));
  }
}

// out[b][t][i] = sum_h hs[t][b][h] * fc_w[i][h] + fc_b[i]
template <int MODE>
__global__ void __launch_bounds__(256) fc_kernel(const void* __restrict__ hsv,
                                                 const float* __restrict__ fcw,
                                                 const float* __restrict__ fcb,
                                                 float* __restrict__ out) {
  const int i = threadIdx.x & 127;
  const int rg = threadIdx.x >> 7;
  const int r0 = blockIdx.x * 64 + rg * 32;
  float acc[32];
  float bias = fcb[i];
#pragma unroll
  for (int r = 0; r < 32; ++r) acc[r] = bias;

  if (MODE == 0) {
    const float* hs = (const float*)hsv;
    for (int k = 0; k < Hn; k += 4) {
      float4 w4 = *(const float4*)(fcw + (size_t)i * Hn + k);
#pragma unroll
      for (int r = 0; r < 32; ++r) {
        float4 h4 = *(const float4*)(hs + (size_t)(r0 + r) * Hn + k);
        acc[r] = fmaf(w4.x, h4.x,
                 fmaf(w4.y, h4.y, fmaf(w4.z, h4.z, fmaf(w4.w, h4.w, acc[r]))));
      }
    }
  } else {
    const unsigned short* hs = (const unsigned short*)hsv;
    for (int k = 0; k < Hn; k += 8) {
      float4 w4a = *(const float4*)(fcw + (size_t)i * Hn + k);
      float4 w4b = *(const float4*)(fcw + (size_t)i * Hn + k + 4);
#pragma unroll
      for (int r = 0; r < 32; ++r) {
        short8 h8 = *(const short8*)(hs + (size_t)(r0 + r) * Hn + k);
        float s = fmaf(bf2f((unsigned short)h8[0]), w4a.x,
                  fmaf(bf2f((unsigned short)h8[1]), w4a.y,
                  fmaf(bf2f((unsigned short)h8[2]), w4a.z,
                  fmaf(bf2f((unsigned short)h8[3]), w4a.w, acc[r]))));
        acc[r] = fmaf(bf2f((unsigned short)h8[4]), w4b.x,
                 fmaf(bf2f((unsigned short)h8[5]), w4b.y,
                 fmaf(bf2f((unsigned short)h8[6]), w4b.z,
                 fmaf(bf2f((unsigned short)h8[7]), w4b.w, s))));
      }
    }
  }
#pragma unroll
  for (int r = 0; r < 32; ++r) {
    int row = r0 + r;  // row = t*64 + b
    out[(size_t)(row & 63) * (Tn * In) + (size_t)(row >> 6) * In + i] = acc[r];
  }
}

extern "C" void kernel_launch(void* const* d_in, const int* in_sizes, int n_in,
                              void* d_out, int out_size, void* d_ws,
                              size_t ws_size, hipStream_t stream) {
  const float* x    = (const float*)d_in[0];
  const float* W_ih = (const float*)d_in[1];
  const float* W_hh = (const float*)d_in[2];
  const float* b_ih = (const float*)d_in[3];
  const float* b_hh = (const float*)d_in[4];
  const float* fc_w = (const float*)d_in[5];
  const float* fc_b = (const float*)d_in[6];
  float* out = (float*)d_out;

  const size_t hs_f32_b = (size_t)Tn * Bn * Hn * 4;      // 128 MiB
  const size_t hs_b16_b = hs_f32_b / 2;                  // 64 MiB
  const size_t x_b = (size_t)Bn * Tn * In * 2;           // 8 MiB
  const size_t pp_b = (size_t)NGn * 2 * GBn * Hn * 2;    // 256 KiB
  int f32mode = (ws_size >= hs_f32_b + x_b + pp_b + 65536) ? 1 : 0;
  size_t hs_b = f32mode ? hs_f32_b : hs_b16_b;

  char* wsc = (char*)d_ws;
  float* hs_f32 = (float*)wsc;
  unsigned short* hs_b16 = (unsigned short*)wsc;
  unsigned short* xb = (unsigned short*)(wsc + hs_b);
  unsigned short* pp = (unsigned short*)(wsc + hs_b + x_b);
  unsigned* bar = (unsigned*)(wsc + hs_b + x_b + pp_b);

  (void)hipMemsetAsync(bar, 0, 4096, stream);
  hipLaunchKernelGGL(xcvt_kernel, dim3((Bn * Tn * In) / (256 * 8)), dim3(256),
                     0, stream, x, xb);
  hipLaunchKernelGGL(lstm_kernel, dim3(256), dim3(256), 0, stream, xb, W_ih,
                     W_hh, b_ih, b_hh, hs_f32, hs_b16, pp, bar, f32mode);
  if (f32mode)
    hipLaunchKernelGGL(fc_kernel<0>, dim3((Tn * Bn) / 64), dim3(256), 0, stream,
                       (const void*)hs_f32, fc_w, fc_b, out);
  else
    hipLaunchKernelGGL(fc_kernel<1>, dim3((Tn * Bn) / 64), dim3(256), 0, stream,
                       (const void*)hs_b16, fc_w, fc_b, out);
}

// Round 2
// 4961.979 us; speedup vs baseline: 3.1503x; 3.1503x over previous
//
#include <hip/hip_runtime.h>

#define Tn 512
#define Bn 64
#define In 128
#define Hn 1024
#define GBn 16    // batch rows per group
#define NGn 4     // independent batch groups
#define NBLKn 64  // blocks per group
#define NCOLn 16  // H columns per block

typedef __attribute__((ext_vector_type(8))) short short8;
typedef __attribute__((ext_vector_type(4))) float f32x4;

__device__ __forceinline__ short f2bf(float f) {
  unsigned u = __builtin_bit_cast(unsigned, f);
  unsigned r = u + 0x7FFFu + ((u >> 16) & 1u);  // RTNE
  return (short)(r >> 16);
}
__device__ __forceinline__ float sigm(float x) { return 1.f / (1.f + __expf(-x)); }
__device__ __forceinline__ float tanh_f(float x) {
  float ax = fabsf(x);
  float e = __expf(-2.f * ax);
  float t = (1.f - e) / (1.f + e);
  return x < 0.f ? -t : t;
}

// Relaxed agent-scope 16B load as 2x u64 (sc0 sc1: bypasses non-coherent
// L1/L2, reads the coherent memory-side cache -- NO cache maintenance).
__device__ __forceinline__ short8 ld_h16(const unsigned short* p) {
  struct Q { unsigned long long a, b; };
  unsigned long long q0 = __hip_atomic_load((const unsigned long long*)p,
                                            __ATOMIC_RELAXED,
                                            __HIP_MEMORY_SCOPE_AGENT);
  unsigned long long q1 = __hip_atomic_load(((const unsigned long long*)p) + 1,
                                            __ATOMIC_RELAXED,
                                            __HIP_MEMORY_SCOPE_AGENT);
  Q q{q0, q1};
  return __builtin_bit_cast(short8, q);
}

// f32 -> bf16 bits, 8 per thread. Grid must cover n/8 exactly.
__global__ void __launch_bounds__(256) cvt_kernel(const float* __restrict__ x,
                                                  unsigned short* __restrict__ xb) {
  size_t idx = ((size_t)blockIdx.x * 256 + threadIdx.x) * 8;
  float4 a0 = *(const float4*)(x + idx);
  float4 a1 = *(const float4*)(x + idx + 4);
  short8 w;
  w[0] = f2bf(a0.x); w[1] = f2bf(a0.y); w[2] = f2bf(a0.z); w[3] = f2bf(a0.w);
  w[4] = f2bf(a1.x); w[5] = f2bf(a1.y); w[6] = f2bf(a1.z); w[7] = f2bf(a1.w);
  *(short8*)(xb + idx) = w;
}

__global__ void __launch_bounds__(256, 1) lstm_kernel(
    const unsigned short* __restrict__ xb, const float* __restrict__ W_ih,
    const float* __restrict__ W_hh, const float* __restrict__ b_ih,
    const float* __restrict__ b_hh, unsigned short* __restrict__ hsb,
    unsigned short* __restrict__ pp, unsigned* __restrict__ bar) {
  const int bid = blockIdx.x;
  const int grp = bid >> 6;   // batch group 0..3
  const int hc = bid & 63;    // H-chunk 0..63 (16 cols each)
  const int wid = threadIdx.x >> 6;  // wave = gate (i,f,g,o)
  const int lane = threadIdx.x & 63;
  const int rowsel = lane & 15;
  const int k8 = (lane >> 4) * 8;

  __shared__ float gates_s[4][16][16];
  __shared__ float bias_s[4][16];

  if (threadIdx.x < 64) {
    int gg = threadIdx.x >> 4, cc = threadIdx.x & 15;
    int idx = gg * Hn + hc * NCOLn + cc;
    bias_s[gg][cc] = b_ih[idx] + b_hh[idx];
  }

  // --- weights -> registers (B-fragments, bf16 bits). One-time. ---
  const int wrow = wid * Hn + hc * NCOLn + rowsel;  // gate row in [0,4096)
  short8 whh[32];
#pragma unroll
  for (int kt = 0; kt < 32; ++kt) {
    const float* p = W_hh + (size_t)wrow * Hn + kt * 32 + k8;
    float4 a0 = *(const float4*)p;
    float4 a1 = *(const float4*)(p + 4);
    short8 w;
    w[0] = f2bf(a0.x); w[1] = f2bf(a0.y); w[2] = f2bf(a0.z); w[3] = f2bf(a0.w);
    w[4] = f2bf(a1.x); w[5] = f2bf(a1.y); w[6] = f2bf(a1.z); w[7] = f2bf(a1.w);
    whh[kt] = w;
  }
  short8 wih[4];
#pragma unroll
  for (int kt = 0; kt < 4; ++kt) {
    const float* p = W_ih + (size_t)wrow * In + kt * 32 + k8;
    float4 a0 = *(const float4*)p;
    float4 a1 = *(const float4*)(p + 4);
    short8 w;
    w[0] = f2bf(a0.x); w[1] = f2bf(a0.y); w[2] = f2bf(a0.z); w[3] = f2bf(a0.w);
    w[4] = f2bf(a1.x); w[5] = f2bf(a1.y); w[6] = f2bf(a1.z); w[7] = f2bf(a1.w);
    wih[kt] = w;
  }
  __syncthreads();

  unsigned short* ppg = pp + (size_t)grp * 2 * GBn * Hn;
  unsigned* cnt = bar + grp * 64;
  unsigned* flag = bar + grp * 64 + 32;

  const unsigned short* xrow = xb + (size_t)(grp * GBn + rowsel) * (Tn * In);

  const int prow = threadIdx.x >> 4;  // batch row 0..15 (pointwise owner)
  const int pcol = threadIdx.x & 15;  // H col within chunk
  float c_reg = 0.f;

#pragma clang loop unroll(disable)
  for (int t = 0; t < Tn; ++t) {
    f32x4 acc[4];
#pragma unroll
    for (int q = 0; q < 4; ++q) acc[q] = (f32x4){0.f, 0.f, 0.f, 0.f};

    short8 a[36];
    if (t > 0) {
      const unsigned short* hp =
          ppg + ((t & 1) ^ 1) * (GBn * Hn) + rowsel * Hn + k8;
#pragma unroll
      for (int kt = 0; kt < 32; ++kt) a[kt] = ld_h16(hp + kt * 32);
    }
    {
      const unsigned short* xp = xrow + (size_t)t * In + k8;
#pragma unroll
      for (int kt = 0; kt < 4; ++kt) a[32 + kt] = *(const short8*)(xp + kt * 32);
    }

    if (t > 0) {
#pragma unroll
      for (int kt = 0; kt < 36; ++kt)
        acc[kt & 3] = __builtin_amdgcn_mfma_f32_16x16x32_bf16(
            a[kt], kt < 32 ? whh[kt] : wih[kt - 32], acc[kt & 3], 0, 0, 0);
    } else {
#pragma unroll
      for (int kt = 0; kt < 4; ++kt)
        acc[kt] = __builtin_amdgcn_mfma_f32_16x16x32_bf16(a[32 + kt], wih[kt],
                                                          acc[kt], 0, 0, 0);
    }
    f32x4 asum = (acc[0] + acc[1]) + (acc[2] + acc[3]);
#pragma unroll
    for (int r = 0; r < 4; ++r)
      gates_s[wid][(lane >> 4) * 4 + r][lane & 15] = asum[r];
    __syncthreads();

    // pointwise LSTM cell; thread owns (prow, pcol), c stays in register
    float iv = gates_s[0][prow][pcol] + bias_s[0][pcol];
    float fv = gates_s[1][prow][pcol] + bias_s[1][pcol];
    float gv = gates_s[2][prow][pcol] + bias_s[2][pcol];
    float ov = gates_s[3][prow][pcol] + bias_s[3][pcol];
    float ig = sigm(iv), fg = sigm(fv), og = sigm(ov), gt = tanh_f(gv);
    c_reg = fg * c_reg + ig * gt;
    float hval = og * tanh_f(c_reg);
    unsigned hb = (unsigned)(unsigned short)f2bf(hval);
    unsigned other = __shfl_xor(hb, 1);  // partner col (pcol^1), same row
    if ((threadIdx.x & 1) == 0) {
      unsigned packed = hb | (other << 16);
      // h exchange: relaxed agent store (sc0 sc1) -- no fence needed
      __hip_atomic_store(
          (unsigned*)(ppg + (t & 1) * (GBn * Hn) + prow * Hn + hc * NCOLn + pcol),
          packed, __ATOMIC_RELAXED, __HIP_MEMORY_SCOPE_AGENT);
      size_t hsidx =
          ((size_t)t * Bn + grp * GBn + prow) * Hn + hc * NCOLn + pcol;
      *(unsigned*)(hsb + hsidx) = packed;  // plain: consumed by next kernel
    }

    // ---- group barrier: monotonic counter, relaxed atomics only ----
    __syncthreads();  // compiler emits s_waitcnt vmcnt(0) first -> stores done
    if (threadIdx.x == 0) {
      unsigned target = (unsigned)(t + 1);
      unsigned prev = __hip_atomic_fetch_add(cnt, 1u, __ATOMIC_RELAXED,
                                             __HIP_MEMORY_SCOPE_AGENT);
      if (prev == (unsigned)NBLKn * target - 1u) {
        __hip_atomic_store(flag, target, __ATOMIC_RELAXED,
                           __HIP_MEMORY_SCOPE_AGENT);
      } else {
        while (__hip_atomic_load(flag, __ATOMIC_RELAXED,
                                 __HIP_MEMORY_SCOPE_AGENT) < target) {
          __builtin_amdgcn_s_sleep(1);
        }
      }
    }
    asm volatile("" ::: "memory");
    __syncthreads();
  }
}

// out[b][t][i] = hs[row=t*64+b][:] . fcw_b16[i][:] + fcb[i], via MFMA.
// Block: 16 hs-rows x all 128 i. Wave w covers i-tiles [32w,32w+16),[32w+16,32w+32).
__global__ void __launch_bounds__(256) fc_mfma_kernel(
    const unsigned short* __restrict__ hsb, const unsigned short* __restrict__ fwb,
    const float* __restrict__ fcb, float* __restrict__ out) {
  const int wid = threadIdx.x >> 6;
  const int lane = threadIdx.x & 63;
  const int rowsel = lane & 15;
  const int k8 = (lane >> 4) * 8;
  const int r0 = blockIdx.x * 16;
  const int i0 = wid * 32;
  f32x4 acc0 = {0.f, 0.f, 0.f, 0.f}, acc1 = {0.f, 0.f, 0.f, 0.f};
  const unsigned short* hrow = hsb + (size_t)(r0 + rowsel) * Hn + k8;
  const unsigned short* w0 = fwb + (size_t)(i0 + rowsel) * Hn + k8;
  const unsigned short* w1 = w0 + 16 * Hn;
#pragma unroll 8
  for (int kt = 0; kt < 32; ++kt) {
    short8 a = *(const short8*)(hrow + kt * 32);
    short8 b0 = *(const short8*)(w0 + kt * 32);
    short8 b1 = *(const short8*)(w1 + kt * 32);
    acc0 = __builtin_amdgcn_mfma_f32_16x16x32_bf16(a, b0, acc0, 0, 0, 0);
    acc1 = __builtin_amdgcn_mfma_f32_16x16x32_bf16(a, b1, acc1, 0, 0, 0);
  }
  const int n = lane & 15;
  float bias0 = fcb[i0 + n], bias1 = fcb[i0 + 16 + n];
#pragma unroll
  for (int r = 0; r < 4; ++r) {
    int row = r0 + (lane >> 4) * 4 + r;  // row = t*64 + b
    float* op = out + ((size_t)(row & 63) * Tn + (row >> 6)) * In;
    op[i0 + n] = acc0[r] + bias0;
    op[i0 + 16 + n] = acc1[r] + bias1;
  }
}

extern "C" void kernel_launch(void* const* d_in, const int* in_sizes, int n_in,
                              void* d_out, int out_size, void* d_ws,
                              size_t ws_size, hipStream_t stream) {
  const float* x    = (const float*)d_in[0];
  const float* W_ih = (const float*)d_in[1];
  const float* W_hh = (const float*)d_in[2];
  const float* b_ih = (const float*)d_in[3];
  const float* b_hh = (const float*)d_in[4];
  const float* fc_w = (const float*)d_in[5];
  const float* fc_b = (const float*)d_in[6];
  float* out = (float*)d_out;

  const size_t hs_b = (size_t)Tn * Bn * Hn * 2;        // 64 MiB bf16 hs
  const size_t x_b  = (size_t)Bn * Tn * In * 2;        // 8 MiB bf16 x
  const size_t fw_b = (size_t)In * Hn * 2;             // 256 KiB bf16 fc_w
  const size_t pp_b = (size_t)NGn * 2 * GBn * Hn * 2;  // 256 KiB ping-pong

  char* wsc = (char*)d_ws;
  unsigned short* hsb = (unsigned short*)wsc;
  unsigned short* xb  = (unsigned short*)(wsc + hs_b);
  unsigned short* fwb = (unsigned short*)(wsc + hs_b + x_b);
  unsigned short* pp  = (unsigned short*)(wsc + hs_b + x_b + fw_b);
  unsigned* bar = (unsigned*)(wsc + hs_b + x_b + fw_b + pp_b);

  (void)hipMemsetAsync(bar, 0, 4096, stream);
  hipLaunchKernelGGL(cvt_kernel, dim3((Bn * Tn * In) / (256 * 8)), dim3(256),
                     0, stream, x, xb);
  hipLaunchKernelGGL(cvt_kernel, dim3((In * Hn) / (256 * 8)), dim3(256), 0,
                     stream, fc_w, fwb);
  hipLaunchKernelGGL(lstm_kernel, dim3(256), dim3(256), 0, stream, xb, W_ih,
                     W_hh, b_ih, b_hh, hsb, pp, bar);
  hipLaunchKernelGGL(fc_mfma_kernel, dim3((Tn * Bn) / 16), dim3(256), 0,
                     stream, hsb, fwb, fc_b, out);
}

// Round 3
// 2328.688 us; speedup vs baseline: 6.7126x; 2.1308x over previous
//
#include <hip/hip_runtime.h>

#define Tn 512
#define Bn 64
#define In 128
#define Hn 1024
#define GBn 16    // batch rows per group
#define NGn 4     // independent batch groups
#define NBLKn 64  // blocks per group
#define NCOLn 16  // H columns per block

typedef __attribute__((ext_vector_type(8))) short short8;
typedef __attribute__((ext_vector_type(4))) float f32x4;

__device__ __forceinline__ short f2bf(float f) {
  unsigned u = __builtin_bit_cast(unsigned, f);
  unsigned r = u + 0x7FFFu + ((u >> 16) & 1u);  // RTNE
  return (short)(r >> 16);
}
__device__ __forceinline__ float sigm(float x) { return 1.f / (1.f + __expf(-x)); }
__device__ __forceinline__ float tanh_f(float x) {
  float ax = fabsf(x);
  float e = __expf(-2.f * ax);
  float t = (1.f - e) / (1.f + e);
  return x < 0.f ? -t : t;
}

// Relaxed agent-scope 16B load as 2x u64 (sc0 sc1: bypasses non-coherent
// L1/L2 -- reads the coherent memory-side cache, no cache maintenance).
__device__ __forceinline__ short8 ld_h16(const unsigned short* p) {
  struct Q { unsigned long long a, b; };
  unsigned long long q0 = __hip_atomic_load((const unsigned long long*)p,
                                            __ATOMIC_RELAXED,
                                            __HIP_MEMORY_SCOPE_AGENT);
  unsigned long long q1 = __hip_atomic_load(((const unsigned long long*)p) + 1,
                                            __ATOMIC_RELAXED,
                                            __HIP_MEMORY_SCOPE_AGENT);
  Q q{q0, q1};
  return __builtin_bit_cast(short8, q);
}

// f32 -> bf16 bits, 8 per thread. Grid must cover n/8 exactly.
__global__ void __launch_bounds__(256) cvt_kernel(const float* __restrict__ x,
                                                  unsigned short* __restrict__ xb) {
  size_t idx = ((size_t)blockIdx.x * 256 + threadIdx.x) * 8;
  float4 a0 = *(const float4*)(x + idx);
  float4 a1 = *(const float4*)(x + idx + 4);
  short8 w;
  w[0] = f2bf(a0.x); w[1] = f2bf(a0.y); w[2] = f2bf(a0.z); w[3] = f2bf(a0.w);
  w[4] = f2bf(a1.x); w[5] = f2bf(a1.y); w[6] = f2bf(a1.z); w[7] = f2bf(a1.w);
  *(short8*)(xb + idx) = w;
}

__global__ void __launch_bounds__(256, 1) lstm_kernel(
    const unsigned short* __restrict__ xb, const float* __restrict__ W_ih,
    const float* __restrict__ W_hh, const float* __restrict__ b_ih,
    const float* __restrict__ b_hh, unsigned short* __restrict__ hsb,
    unsigned short* __restrict__ pp, unsigned* __restrict__ bar) {
  const int bid = blockIdx.x;
  const int grp = bid >> 6;   // batch group 0..3
  const int hc = bid & 63;    // H-chunk 0..63 (16 cols each)
  const int wid = threadIdx.x >> 6;  // wave = gate (i,f,g,o)
  const int lane = threadIdx.x & 63;
  const int rowsel = lane & 15;
  const int k8 = (lane >> 4) * 8;

  __shared__ unsigned short h_lds[GBn * Hn];  // 32 KB staged h (swizzled)
  __shared__ float gates_s[4][16][16];
  __shared__ float bias_s[4][16];

  if (threadIdx.x < 64) {
    int gg = threadIdx.x >> 4, cc = threadIdx.x & 15;
    int idx = gg * Hn + hc * NCOLn + cc;
    bias_s[gg][cc] = b_ih[idx] + b_hh[idx];
  }

  // --- weights -> registers (B-fragments, bf16 bits). One-time. ---
  const int wrow = wid * Hn + hc * NCOLn + rowsel;  // gate row in [0,4096)
  short8 whh[32];
#pragma unroll
  for (int kt = 0; kt < 32; ++kt) {
    const float* p = W_hh + (size_t)wrow * Hn + kt * 32 + k8;
    float4 a0 = *(const float4*)p;
    float4 a1 = *(const float4*)(p + 4);
    short8 w;
    w[0] = f2bf(a0.x); w[1] = f2bf(a0.y); w[2] = f2bf(a0.z); w[3] = f2bf(a0.w);
    w[4] = f2bf(a1.x); w[5] = f2bf(a1.y); w[6] = f2bf(a1.z); w[7] = f2bf(a1.w);
    whh[kt] = w;
  }
  short8 wih[4];
#pragma unroll
  for (int kt = 0; kt < 4; ++kt) {
    const float* p = W_ih + (size_t)wrow * In + kt * 32 + k8;
    float4 a0 = *(const float4*)p;
    float4 a1 = *(const float4*)(p + 4);
    short8 w;
    w[0] = f2bf(a0.x); w[1] = f2bf(a0.y); w[2] = f2bf(a0.z); w[3] = f2bf(a0.w);
    w[4] = f2bf(a1.x); w[5] = f2bf(a1.y); w[6] = f2bf(a1.z); w[7] = f2bf(a1.w);
    wih[kt] = w;
  }
  __syncthreads();

  unsigned short* ppg = pp + (size_t)grp * 2 * GBn * Hn;
  unsigned* flg = bar + grp * 64;  // 64 ready-flags per group

  const unsigned short* xrow = xb + (size_t)(grp * GBn + rowsel) * (Tn * In);

  const int prow = threadIdx.x >> 4;  // batch row 0..15 (pointwise owner)
  const int pcol = threadIdx.x & 15;  // H col within chunk
  float c_reg = 0.f;

  // fragment-read LDS base (bytes), swizzle applied per kt below
  const int rswz = (rowsel & 7) << 4;
  const int rbase = rowsel * 2048 + k8 * 2;

#pragma clang loop unroll(disable)
  for (int t = 0; t < Tn; ++t) {
    f32x4 acc[4];
#pragma unroll
    for (int q = 0; q < 4; ++q) acc[q] = (f32x4){0.f, 0.f, 0.f, 0.f};

    // x-part first: independent of h, overlaps the flag spin
    {
      const unsigned short* xp = xrow + (size_t)t * In + k8;
#pragma unroll
      for (int kt = 0; kt < 4; ++kt) {
        short8 a = *(const short8*)(xp + kt * 32);
        acc[kt] = __builtin_amdgcn_mfma_f32_16x16x32_bf16(a, wih[kt], acc[kt],
                                                          0, 0, 0);
      }
    }

    if (t > 0) {
      // ---- spin: all 64 producer blocks of this group posted step t-1 ----
      unsigned tgt = (unsigned)t;
      while (true) {
        unsigned f = __hip_atomic_load(&flg[lane], __ATOMIC_RELAXED,
                                       __HIP_MEMORY_SCOPE_AGENT);
        if (__all(f >= tgt)) break;
        __builtin_amdgcn_s_sleep(1);
      }
      asm volatile("" ::: "memory");

      // ---- cooperative load h[t-1] -> LDS (each wave: 4 rows) ----
      const unsigned short* src = ppg + ((t - 1) & 1) * (GBn * Hn);
#pragma unroll
      for (int j = 0; j < 8; ++j) {
        int off_e = wid * 4096 + j * 512 + lane * 8;  // element offset
        short8 v = ld_h16(src + off_e);
        int row = wid * 4 + (j >> 1);                 // compile-time per j
        int byteoff = (off_e * 2) ^ ((row & 7) << 4); // XOR-swizzle
        *(short8*)((char*)h_lds + byteoff) = v;
      }
      __syncthreads();

      // ---- h-part MFMAs from LDS ----
#pragma unroll
      for (int kt = 0; kt < 32; ++kt) {
        short8 a = *(const short8*)((char*)h_lds + ((rbase + kt * 64) ^ rswz));
        acc[kt & 3] = __builtin_amdgcn_mfma_f32_16x16x32_bf16(a, whh[kt],
                                                              acc[kt & 3], 0, 0, 0);
      }
    }

    f32x4 asum = (acc[0] + acc[1]) + (acc[2] + acc[3]);
#pragma unroll
    for (int r = 0; r < 4; ++r)
      gates_s[wid][(lane >> 4) * 4 + r][lane & 15] = asum[r];
    __syncthreads();

    // pointwise LSTM cell; thread owns (prow, pcol), c stays in register
    float iv = gates_s[0][prow][pcol] + bias_s[0][pcol];
    float fv = gates_s[1][prow][pcol] + bias_s[1][pcol];
    float gv = gates_s[2][prow][pcol] + bias_s[2][pcol];
    float ov = gates_s[3][prow][pcol] + bias_s[3][pcol];
    float ig = sigm(iv), fg = sigm(fv), og = sigm(ov), gt = tanh_f(gv);
    c_reg = fg * c_reg + ig * gt;
    float hval = og * tanh_f(c_reg);
    unsigned hb = (unsigned)(unsigned short)f2bf(hval);
    unsigned other = __shfl_xor(hb, 1);  // partner col (pcol^1), same row
    if ((threadIdx.x & 1) == 0) {
      unsigned packed = hb | (other << 16);
      // h exchange: relaxed agent store (sc1) -- no cache maintenance
      __hip_atomic_store(
          (unsigned*)(ppg + (t & 1) * (GBn * Hn) + prow * Hn + hc * NCOLn + pcol),
          packed, __ATOMIC_RELAXED, __HIP_MEMORY_SCOPE_AGENT);
      size_t hsidx =
          ((size_t)t * Bn + grp * GBn + prow) * Hn + hc * NCOLn + pcol;
      *(unsigned*)(hsb + hsidx) = packed;  // plain: consumed by next kernel
    }

    // every wave: s_waitcnt vmcnt(0) before s_barrier -> all h stores acked
    __syncthreads();
    if (threadIdx.x == 0)
      __hip_atomic_store(&flg[hc], (unsigned)(t + 1), __ATOMIC_RELAXED,
                         __HIP_MEMORY_SCOPE_AGENT);
  }
}

// out[b][t][i] = hs[row=t*64+b][:] . fcw_b16[i][:] + fcb[i], via MFMA.
__global__ void __launch_bounds__(256) fc_mfma_kernel(
    const unsigned short* __restrict__ hsb, const unsigned short* __restrict__ fwb,
    const float* __restrict__ fcb, float* __restrict__ out) {
  const int wid = threadIdx.x >> 6;
  const int lane = threadIdx.x & 63;
  const int rowsel = lane & 15;
  const int k8 = (lane >> 4) * 8;
  const int r0 = blockIdx.x * 16;
  const int i0 = wid * 32;
  f32x4 acc0 = {0.f, 0.f, 0.f, 0.f}, acc1 = {0.f, 0.f, 0.f, 0.f};
  const unsigned short* hrow = hsb + (size_t)(r0 + rowsel) * Hn + k8;
  const unsigned short* w0 = fwb + (size_t)(i0 + rowsel) * Hn + k8;
  const unsigned short* w1 = w0 + 16 * Hn;
#pragma unroll 8
  for (int kt = 0; kt < 32; ++kt) {
    short8 a = *(const short8*)(hrow + kt * 32);
    short8 b0 = *(const short8*)(w0 + kt * 32);
    short8 b1 = *(const short8*)(w1 + kt * 32);
    acc0 = __builtin_amdgcn_mfma_f32_16x16x32_bf16(a, b0, acc0, 0, 0, 0);
    acc1 = __builtin_amdgcn_mfma_f32_16x16x32_bf16(a, b1, acc1, 0, 0, 0);
  }
  const int n = lane & 15;
  float bias0 = fcb[i0 + n], bias1 = fcb[i0 + 16 + n];
#pragma unroll
  for (int r = 0; r < 4; ++r) {
    int row = r0 + (lane >> 4) * 4 + r;  // row = t*64 + b
    float* op = out + ((size_t)(row & 63) * Tn + (row >> 6)) * In;
    op[i0 + n] = acc0[r] + bias0;
    op[i0 + 16 + n] = acc1[r] + bias1;
  }
}

extern "C" void kernel_launch(void* const* d_in, const int* in_sizes, int n_in,
                              void* d_out, int out_size, void* d_ws,
                              size_t ws_size, hipStream_t stream) {
  const float* x    = (const float*)d_in[0];
  const float* W_ih = (const float*)d_in[1];
  const float* W_hh = (const float*)d_in[2];
  const float* b_ih = (const float*)d_in[3];
  const float* b_hh = (const float*)d_in[4];
  const float* fc_w = (const float*)d_in[5];
  const float* fc_b = (const float*)d_in[6];
  float* out = (float*)d_out;

  const size_t hs_b = (size_t)Tn * Bn * Hn * 2;        // 64 MiB bf16 hs
  const size_t x_b  = (size_t)Bn * Tn * In * 2;        // 8 MiB bf16 x
  const size_t fw_b = (size_t)In * Hn * 2;             // 256 KiB bf16 fc_w
  const size_t pp_b = (size_t)NGn * 2 * GBn * Hn * 2;  // 256 KiB ping-pong

  char* wsc = (char*)d_ws;
  unsigned short* hsb = (unsigned short*)wsc;
  unsigned short* xb  = (unsigned short*)(wsc + hs_b);
  unsigned short* fwb = (unsigned short*)(wsc + hs_b + x_b);
  unsigned short* pp  = (unsigned short*)(wsc + hs_b + x_b + fw_b);
  unsigned* bar = (unsigned*)(wsc + hs_b + x_b + fw_b + pp_b);

  (void)hipMemsetAsync(bar, 0, 4096, stream);
  hipLaunchKernelGGL(cvt_kernel, dim3((Bn * Tn * In) / (256 * 8)), dim3(256),
                     0, stream, x, xb);
  hipLaunchKernelGGL(cvt_kernel, dim3((In * Hn) / (256 * 8)), dim3(256), 0,
                     stream, fc_w, fwb);
  hipLaunchKernelGGL(lstm_kernel, dim3(256), dim3(256), 0, stream, xb, W_ih,
                     W_hh, b_ih, b_hh, hsb, pp, bar);
  hipLaunchKernelGGL(fc_mfma_kernel, dim3((Tn * Bn) / 16), dim3(256), 0,
                     stream, hsb, fwb, fc_b, out);
}